// Round 1
// baseline (4404.045 us; speedup 1.0000x reference)
//
#include <hip/hip_runtime.h>

// Problem constants (shapes fixed by the reference).
#define FIN   128
#define FHID  128
#define FOUT  64
#define FFC   256

// ---------------------------------------------------------------------------
// degree count: deg[dst] += 1 per edge (self-loop added analytically later)
__global__ void deg_kernel(const int* __restrict__ dst, float* __restrict__ deg, int E) {
    int i = blockIdx.x * blockDim.x + threadIdx.x;
    if (i < E) atomicAdd(&deg[dst[i]], 1.0f);
}

// dinv[i] = rsqrt(deg[i] + 1)   (+1 = self-loop; always > 0)
__global__ void dinv_kernel(float* __restrict__ deg, int n) {
    int i = blockIdx.x * blockDim.x + threadIdx.x;
    if (i < n) deg[i] = rsqrtf(deg[i] + 1.0f);
}

// ---------------------------------------------------------------------------
// Classic 64x64 fp32 tiled GEMM: C[M,Ncol] = A[M,K] @ B[K,Ncol] (+bias)(relu)
// 256 threads, 4x4 micro-tile per thread. K, Ncol multiples of 16/64; M ragged.
__global__ __launch_bounds__(256) void gemm_kernel(
    const float* __restrict__ A, const float* __restrict__ B,
    const float* __restrict__ bias, float* __restrict__ C,
    int M, int Ncol, int K, int relu)
{
    __shared__ float As[16][64 + 1];   // [k][m]
    __shared__ float Bs[16][64 + 1];   // [k][n]
    const int tid = threadIdx.x;
    const int tx = tid & 15;           // n direction
    const int ty = tid >> 4;           // m direction
    const int row0 = blockIdx.y * 64;
    const int col0 = blockIdx.x * 64;

    float acc[4][4] = {};

    for (int k0 = 0; k0 < K; k0 += 16) {
        // A tile: 64 rows x 16 k. thread -> row = tid/4, k-chunk = (tid%4)*4
        {
            int r = tid >> 2;
            int c = (tid & 3) << 2;
            float4 v = make_float4(0.f, 0.f, 0.f, 0.f);
            int gr = row0 + r;
            if (gr < M) v = *(const float4*)(A + (long)gr * K + k0 + c);
            As[c + 0][r] = v.x; As[c + 1][r] = v.y;
            As[c + 2][r] = v.z; As[c + 3][r] = v.w;
        }
        // B tile: 16 k x 64 cols. thread -> k = tid/16, col-chunk = (tid%16)*4
        {
            int kr = tid >> 4;
            int cc = (tid & 15) << 2;
            float4 v = *(const float4*)(B + (long)(k0 + kr) * Ncol + col0 + cc);
            Bs[kr][cc + 0] = v.x; Bs[kr][cc + 1] = v.y;
            Bs[kr][cc + 2] = v.z; Bs[kr][cc + 3] = v.w;
        }
        __syncthreads();

        #pragma unroll
        for (int kk = 0; kk < 16; kk++) {
            float a[4], b[4];
            #pragma unroll
            for (int i = 0; i < 4; i++) a[i] = As[kk][ty * 4 + i];
            #pragma unroll
            for (int j = 0; j < 4; j++) b[j] = Bs[kk][tx * 4 + j];
            #pragma unroll
            for (int i = 0; i < 4; i++)
                #pragma unroll
                for (int j = 0; j < 4; j++)
                    acc[i][j] += a[i] * b[j];
        }
        __syncthreads();
    }

    #pragma unroll
    for (int i = 0; i < 4; i++) {
        int r = row0 + ty * 4 + i;
        if (r >= M) continue;
        int c0 = col0 + tx * 4;
        float4 o;
        float* pv = &o.x;
        #pragma unroll
        for (int j = 0; j < 4; j++) {
            float v = acc[i][j];
            if (bias) v += bias[c0 + j];
            if (relu) v = fmaxf(v, 0.f);
            pv[j] = v;
        }
        *(float4*)(C + (long)r * Ncol + c0) = o;
    }
}

// ---------------------------------------------------------------------------
// Push-style scatter: agg[dst] += dinv[src]*dinv[dst] * t[src]
// F/4 threads per edge, each handles one float4 (4 scalar atomics).
__global__ void scatter_kernel(
    const float* __restrict__ t, const int* __restrict__ src,
    const int* __restrict__ dst, const float* __restrict__ dinv,
    float* __restrict__ agg, int E, int F, int shift)
{
    long tid = (long)blockIdx.x * blockDim.x + threadIdx.x;
    long total = (long)E << shift;
    if (tid >= total) return;
    int e = (int)(tid >> shift);
    int f = ((int)tid & ((1 << shift) - 1)) << 2;
    int s = src[e], d = dst[e];
    float w = dinv[s] * dinv[d];
    float4 v = *(const float4*)(t + (long)s * F + f);
    float* p = agg + (long)d * F + f;
    atomicAdd(p + 0, w * v.x);
    atomicAdd(p + 1, w * v.y);
    atomicAdd(p + 2, w * v.z);
    atomicAdd(p + 3, w * v.w);
}

// h = relu(agg + dinv^2 * t + bias)   (written into agg in place)
__global__ void finalize_relu_kernel(
    float* __restrict__ agg, const float* __restrict__ t,
    const float* __restrict__ dinv, const float* __restrict__ bias,
    long n, int Fmask, int logF)
{
    long i = (long)blockIdx.x * blockDim.x + threadIdx.x;
    if (i >= n) return;
    int node = (int)(i >> logF);
    int f = (int)i & Fmask;
    float w = dinv[node];
    float v = agg[i] + w * w * t[i] + bias[f];
    agg[i] = fmaxf(v, 0.f);
}

// z = 0.5*(agg + dinv^2*t + bias) + 0.5*xfc   (written into t in place)
__global__ void finalize_z_kernel(
    const float* __restrict__ agg, float* __restrict__ t,
    const float* __restrict__ dinv, const float* __restrict__ bias,
    const float* __restrict__ xfc, long n)
{
    long i = (long)blockIdx.x * blockDim.x + threadIdx.x;
    if (i >= n) return;
    int node = (int)(i >> 6);
    int f = (int)i & 63;
    float w = dinv[node];
    float xg = agg[i] + w * w * t[i] + bias[f];
    t[i] = 0.5f * xg + 0.5f * xfc[i];
}

// out[q] = dot(z[a], z[b]) over 64 dims; 16 threads/query, float4 each.
__global__ void decode_kernel(
    const float* __restrict__ z, const int* __restrict__ eli,
    float* __restrict__ out, int Q)
{
    int tid = blockIdx.x * blockDim.x + threadIdx.x;
    int q = tid >> 4;
    if (q >= Q) return;
    int lane = tid & 15;
    int a = eli[q];
    int b = eli[Q + q];
    float4 va = *(const float4*)(z + (long)a * FOUT + lane * 4);
    float4 vb = *(const float4*)(z + (long)b * FOUT + lane * 4);
    float s = va.x * vb.x + va.y * vb.y + va.z * vb.z + va.w * vb.w;
    s += __shfl_down(s, 8, 16);
    s += __shfl_down(s, 4, 16);
    s += __shfl_down(s, 2, 16);
    s += __shfl_down(s, 1, 16);
    if (lane == 0) out[q] = s;
}

// ---------------------------------------------------------------------------
extern "C" void kernel_launch(void* const* d_in, const int* in_sizes, int n_in,
                              void* d_out, int out_size, void* d_ws, size_t ws_size,
                              hipStream_t stream)
{
    const float* x   = (const float*)d_in[0];
    const int*   ei  = (const int*)  d_in[1];
    const int*   eli = (const int*)  d_in[2];
    const float* W1  = (const float*)d_in[3];
    const float* b1  = (const float*)d_in[4];
    const float* W2  = (const float*)d_in[5];
    const float* b2  = (const float*)d_in[6];
    const float* Wf1 = (const float*)d_in[7];
    const float* bf1 = (const float*)d_in[8];
    const float* Wf2 = (const float*)d_in[9];
    const float* bf2 = (const float*)d_in[10];
    float* out = (float*)d_out;

    const int N = in_sizes[0] / FIN;       // 50000
    const int E = in_sizes[1] / 2;         // 1600000
    const int Q = in_sizes[2] / 2;         // 500000
    const int* src = ei;
    const int* dst = ei + E;

    // Workspace layout (floats), reusing the FC scratch for GCN temporaries:
    //   dinv [N] | xfc [N*64] | bufA [N*256]
    //   bufA: f1 (N*256) -> then t1 (N*128) @0 + agg1/h1 (N*128) @N*128
    //         -> then t2/z (N*64) @0 + agg2 (N*64) @N*64
    float* ws   = (float*)d_ws;
    float* dinv = ws;
    float* xfc  = dinv + N;
    float* bufA = xfc + (long)N * FOUT;
    float* f1   = bufA;
    float* t1   = bufA;
    float* agg1 = bufA + (long)N * FHID;   // also h1 after finalize
    float* t2   = bufA;                    // also z after finalize
    float* agg2 = bufA + (long)N * FOUT;

    const int TB = 256;

    // --- degree / normalization ---
    hipMemsetAsync(dinv, 0, sizeof(float) * (size_t)N, stream);
    deg_kernel<<<(E + TB - 1) / TB, TB, 0, stream>>>(dst, dinv, E);
    dinv_kernel<<<(N + TB - 1) / TB, TB, 0, stream>>>(dinv, N);

    // --- FC path first (frees bufA for GCN temporaries) ---
    {   // f1 = relu(x @ Wf1 + bf1)   [N,256]
        dim3 g(FFC / 64, (N + 63) / 64);
        gemm_kernel<<<g, TB, 0, stream>>>(x, Wf1, bf1, f1, N, FFC, FIN, 1);
    }
    {   // xfc = f1 @ Wf2 + bf2       [N,64]
        dim3 g(FOUT / 64, (N + 63) / 64);
        gemm_kernel<<<g, TB, 0, stream>>>(f1, Wf2, bf2, xfc, N, FOUT, FFC, 0);
    }

    // --- GCN layer 1 ---
    {   // t1 = x @ W1   [N,128]
        dim3 g(FHID / 64, (N + 63) / 64);
        gemm_kernel<<<g, TB, 0, stream>>>(x, W1, nullptr, t1, N, FHID, FIN, 0);
    }
    hipMemsetAsync(agg1, 0, sizeof(float) * (size_t)N * FHID, stream);
    {
        long total = (long)E << 5;  // E * (128/4)
        scatter_kernel<<<(total + TB - 1) / TB, TB, 0, stream>>>(
            t1, src, dst, dinv, agg1, E, FHID, 5);
    }
    {
        long n = (long)N * FHID;
        finalize_relu_kernel<<<(n + TB - 1) / TB, TB, 0, stream>>>(
            agg1, t1, dinv, b1, n, FHID - 1, 7);
    }

    // --- GCN layer 2 ---
    {   // t2 = h1 @ W2   [N,64]   (h1 lives in agg1; t2 overwrites t1 region)
        dim3 g(FOUT / 64, (N + 63) / 64);
        gemm_kernel<<<g, TB, 0, stream>>>(agg1, W2, nullptr, t2, N, FOUT, FHID, 0);
    }
    hipMemsetAsync(agg2, 0, sizeof(float) * (size_t)N * FOUT, stream);
    {
        long total = (long)E << 4;  // E * (64/4)
        scatter_kernel<<<(total + TB - 1) / TB, TB, 0, stream>>>(
            t2, src, dst, dinv, agg2, E, FOUT, 4);
    }

    // --- blend:  z = 0.5*x_gcn + 0.5*x_fc  (into t2 region) ---
    {
        long n = (long)N * FOUT;
        finalize_z_kernel<<<(n + TB - 1) / TB, TB, 0, stream>>>(
            agg2, t2, dinv, b2, xfc, n);
    }

    // --- decode ---
    {
        long total = (long)Q * 16;
        decode_kernel<<<(total + TB - 1) / TB, TB, 0, stream>>>(t2, eli, out, Q);
    }
}

// Round 2
// 714.516 us; speedup vs baseline: 6.1637x; 6.1637x over previous
//
#include <hip/hip_runtime.h>

// Problem constants (shapes fixed by the reference).
#define FIN   128
#define FHID  128
#define FOUT  64
#define FFC   256
#define SCAN_B 256

// ---------------------------------------------------------------------------
// bf16 helpers (raw ushort, RNE rounding)
static __device__ __forceinline__ unsigned short f2bf(float f) {
    unsigned int u = __float_as_uint(f);
    u = (u + 0x7fffu + ((u >> 16) & 1u)) >> 16;
    return (unsigned short)u;
}
static __device__ __forceinline__ float bf2f(unsigned short s) {
    return __uint_as_float(((unsigned int)s) << 16);
}

// ---------------------------------------------------------------------------
// CSR build: count in-degree per dst
__global__ void count_kernel(const int* __restrict__ dst, int* __restrict__ rp, int E) {
    int i = blockIdx.x * blockDim.x + threadIdx.x;
    if (i < E) atomicAdd(&rp[dst[i]], 1);
}

// dinv[i] = rsqrt(cnt[i] + 1)  (+1 = self-loop)
__global__ void dinv_kernel(const int* __restrict__ cnt, float* __restrict__ dinv, int n) {
    int i = blockIdx.x * blockDim.x + threadIdx.x;
    if (i < n) dinv[i] = rsqrtf((float)cnt[i] + 1.0f);
}

// 3-kernel exclusive scan over rp[0..n) (n <= SCAN_B*SCAN_B)
__global__ void scan1_kernel(int* __restrict__ rp, int* __restrict__ bsum, int n) {
    __shared__ int tmp[SCAN_B];
    int tid = threadIdx.x;
    int i = blockIdx.x * SCAN_B + tid;
    int v = (i < n) ? rp[i] : 0;
    tmp[tid] = v;
    __syncthreads();
    int acc = v;
    for (int off = 1; off < SCAN_B; off <<= 1) {
        int a = (tid >= off) ? tmp[tid - off] : 0;
        __syncthreads();
        acc += a;
        tmp[tid] = acc;
        __syncthreads();
    }
    if (i < n) rp[i] = acc - v;              // exclusive within block
    if (tid == SCAN_B - 1) bsum[blockIdx.x] = acc;  // block total
}

__global__ void scan2_kernel(int* __restrict__ bsum, int nb) {
    __shared__ int tmp[SCAN_B];
    int tid = threadIdx.x;
    int v = (tid < nb) ? bsum[tid] : 0;
    tmp[tid] = v;
    __syncthreads();
    int acc = v;
    for (int off = 1; off < SCAN_B; off <<= 1) {
        int a = (tid >= off) ? tmp[tid - off] : 0;
        __syncthreads();
        acc += a;
        tmp[tid] = acc;
        __syncthreads();
    }
    if (tid < nb) bsum[tid] = acc - v;       // exclusive block offsets
}

__global__ void scan3_kernel(int* __restrict__ rp, const int* __restrict__ bsum, int n) {
    int i = blockIdx.x * SCAN_B + threadIdx.x;
    if (i < n) rp[i] += bsum[blockIdx.x];
}

// fill: pos = rp[d]++ (atomic); col[pos] = src. Afterwards rp[i] = end of node i.
__global__ void fill_kernel(const int* __restrict__ src, const int* __restrict__ dst,
                            int* __restrict__ rp, int* __restrict__ col, int E) {
    int e = blockIdx.x * blockDim.x + threadIdx.x;
    if (e < E) {
        int d = dst[e];
        int pos = atomicAdd(&rp[d], 1);
        col[pos] = src[e];
    }
}

// ---------------------------------------------------------------------------
// Tiled fp32 GEMM, 64x64 tile, 4x4 micro-tile; A may be bf16, C may be bf16.
template <int ABF, int CBF>
__global__ __launch_bounds__(256) void gemm_t(
    const void* __restrict__ Av, const float* __restrict__ B,
    const float* __restrict__ bias, void* __restrict__ Cv,
    int M, int Ncol, int K, int relu)
{
    __shared__ float As[16][64 + 1];   // [k][m]
    __shared__ float Bs[16][64 + 1];   // [k][n]
    const int tid = threadIdx.x;
    const int tx = tid & 15;           // n direction
    const int ty = tid >> 4;           // m direction
    const int row0 = blockIdx.y * 64;
    const int col0 = blockIdx.x * 64;

    float acc[4][4] = {};

    for (int k0 = 0; k0 < K; k0 += 16) {
        {   // A tile: row = tid/4, k-chunk = (tid%4)*4
            int r = tid >> 2;
            int c = (tid & 3) << 2;
            int gr = row0 + r;
            float4 v = make_float4(0.f, 0.f, 0.f, 0.f);
            if (gr < M) {
                if (ABF) {
                    const ushort4 u = *(const ushort4*)((const unsigned short*)Av + (long)gr * K + k0 + c);
                    v = make_float4(bf2f(u.x), bf2f(u.y), bf2f(u.z), bf2f(u.w));
                } else {
                    v = *(const float4*)((const float*)Av + (long)gr * K + k0 + c);
                }
            }
            As[c + 0][r] = v.x; As[c + 1][r] = v.y;
            As[c + 2][r] = v.z; As[c + 3][r] = v.w;
        }
        {   // B tile: k = tid/16, col-chunk = (tid%16)*4
            int kr = tid >> 4;
            int cc = (tid & 15) << 2;
            float4 v = *(const float4*)(B + (long)(k0 + kr) * Ncol + col0 + cc);
            Bs[kr][cc + 0] = v.x; Bs[kr][cc + 1] = v.y;
            Bs[kr][cc + 2] = v.z; Bs[kr][cc + 3] = v.w;
        }
        __syncthreads();

        #pragma unroll
        for (int kk = 0; kk < 16; kk++) {
            float a[4], b[4];
            #pragma unroll
            for (int i = 0; i < 4; i++) a[i] = As[kk][ty * 4 + i];
            #pragma unroll
            for (int j = 0; j < 4; j++) b[j] = Bs[kk][tx * 4 + j];
            #pragma unroll
            for (int i = 0; i < 4; i++)
                #pragma unroll
                for (int j = 0; j < 4; j++)
                    acc[i][j] += a[i] * b[j];
        }
        __syncthreads();
    }

    #pragma unroll
    for (int i = 0; i < 4; i++) {
        int r = row0 + ty * 4 + i;
        if (r >= M) continue;
        int c0 = col0 + tx * 4;
        float v[4];
        #pragma unroll
        for (int j = 0; j < 4; j++) {
            float t = acc[i][j];
            if (bias) t += bias[c0 + j];
            if (relu) t = fmaxf(t, 0.f);
            v[j] = t;
        }
        if (CBF) {
            ushort4 o = make_ushort4(f2bf(v[0]), f2bf(v[1]), f2bf(v[2]), f2bf(v[3]));
            *(ushort4*)((unsigned short*)Cv + (long)r * Ncol + c0) = o;
        } else {
            float4 o = make_float4(v[0], v[1], v[2], v[3]);
            *(float4*)((float*)Cv + (long)r * Ncol + c0) = o;
        }
    }
}

// ---------------------------------------------------------------------------
// CSR pull, F=128: agg[i] = dinv_i * ( sum_{s in N(i)} dinv_s * x[s] + dinv_i * x[i] )
// 256 thr = 8 nodes x 32 lanes (one float4 per lane).
__global__ __launch_bounds__(256) void pull1_kernel(
    const float* __restrict__ x, const int* __restrict__ rp,
    const int* __restrict__ col, const float* __restrict__ dinv,
    float* __restrict__ agg, int N)
{
    int tid = threadIdx.x;
    int node = blockIdx.x * 8 + (tid >> 5);
    if (node >= N) return;
    int f = (tid & 31) << 2;
    float di = dinv[node];
    float4 xi = *(const float4*)(x + (long)node * FIN + f);
    float4 acc = make_float4(di * xi.x, di * xi.y, di * xi.z, di * xi.w);
    int beg = node ? rp[node - 1] : 0;
    int end = rp[node];
    for (int j = beg; j < end; j++) {
        int s = col[j];
        float w = dinv[s];
        float4 v = *(const float4*)(x + (long)s * FIN + f);
        acc.x += w * v.x; acc.y += w * v.y;
        acc.z += w * v.z; acc.w += w * v.w;
    }
    float4 o = make_float4(di * acc.x, di * acc.y, di * acc.z, di * acc.w);
    *(float4*)(agg + (long)node * FIN + f) = o;
}

// CSR pull, F=64, fused self-loop + bias + blend:
// z[i] = 0.5*(dinv_i*(sum + dinv_i*t2[i]) + b2) + 0.5*xfc[i]
__global__ __launch_bounds__(256) void pull2_kernel(
    const float* __restrict__ t2, const int* __restrict__ rp,
    const int* __restrict__ col, const float* __restrict__ dinv,
    const float* __restrict__ xfc, const float* __restrict__ b2,
    float* __restrict__ z, int N)
{
    int tid = threadIdx.x;
    int node = blockIdx.x * 16 + (tid >> 4);
    if (node >= N) return;
    int f = (tid & 15) << 2;
    float di = dinv[node];
    float4 ti = *(const float4*)(t2 + (long)node * FOUT + f);
    float4 acc = make_float4(di * ti.x, di * ti.y, di * ti.z, di * ti.w);
    int beg = node ? rp[node - 1] : 0;
    int end = rp[node];
    for (int j = beg; j < end; j++) {
        int s = col[j];
        float w = dinv[s];
        float4 v = *(const float4*)(t2 + (long)s * FOUT + f);
        acc.x += w * v.x; acc.y += w * v.y;
        acc.z += w * v.z; acc.w += w * v.w;
    }
    float4 bb = *(const float4*)(b2 + f);
    float4 xf = *(const float4*)(xfc + (long)node * FOUT + f);
    float4 o;
    o.x = 0.5f * (di * acc.x + bb.x) + 0.5f * xf.x;
    o.y = 0.5f * (di * acc.y + bb.y) + 0.5f * xf.y;
    o.z = 0.5f * (di * acc.z + bb.z) + 0.5f * xf.z;
    o.w = 0.5f * (di * acc.w + bb.w) + 0.5f * xf.w;
    *(float4*)(z + (long)node * FOUT + f) = o;
}

// out[q] = dot(z[a], z[b]) over 64 dims; 16 threads/query, float4 each.
__global__ void decode_kernel(
    const float* __restrict__ z, const int* __restrict__ eli,
    float* __restrict__ out, int Q)
{
    int tid = blockIdx.x * blockDim.x + threadIdx.x;
    int q = tid >> 4;
    if (q >= Q) return;
    int lane = tid & 15;
    int a = eli[q];
    int b = eli[Q + q];
    float4 va = *(const float4*)(z + (long)a * FOUT + lane * 4);
    float4 vb = *(const float4*)(z + (long)b * FOUT + lane * 4);
    float s = va.x * vb.x + va.y * vb.y + va.z * vb.z + va.w * vb.w;
    s += __shfl_down(s, 8, 16);
    s += __shfl_down(s, 4, 16);
    s += __shfl_down(s, 2, 16);
    s += __shfl_down(s, 1, 16);
    if (lane == 0) out[q] = s;
}

// ---------------------------------------------------------------------------
extern "C" void kernel_launch(void* const* d_in, const int* in_sizes, int n_in,
                              void* d_out, int out_size, void* d_ws, size_t ws_size,
                              hipStream_t stream)
{
    const float* x   = (const float*)d_in[0];
    const int*   ei  = (const int*)  d_in[1];
    const int*   eli = (const int*)  d_in[2];
    const float* W1  = (const float*)d_in[3];
    const float* b1  = (const float*)d_in[4];
    const float* W2  = (const float*)d_in[5];
    const float* b2  = (const float*)d_in[6];
    const float* Wf1 = (const float*)d_in[7];
    const float* bf1 = (const float*)d_in[8];
    const float* Wf2 = (const float*)d_in[9];
    const float* bf2 = (const float*)d_in[10];
    float* out = (float*)d_out;

    const int N = in_sizes[0] / FIN;       // 50000
    const int E = in_sizes[1] / 2;         // 1600000
    const int Q = in_sizes[2] / 2;         // 500000
    const int* src = ei;
    const int* dst = ei + E;

    // Workspace layout (elements padded to keep 16B alignment):
    //   dinv: N f32 | rp: N+1 int (pad->N+4) | bsum: 256 int | col: E int
    //   bufA: N*128 f32  -> [0:N*64) xfc f32; [N*64:N*128) h1 bf16
    //   bufB: N*128 f32  -> f1 bf16 (N*256 bf16) -> aggx f32 (N*128)
    //                      -> t2 f32 [0:N*64) + z f32 [N*64:N*128)
    // Peak = (N + N+4 + 256 + E + 2*N*128)*4 B ~= 58 MB.
    float* ws   = (float*)d_ws;
    float* dinv = ws;
    int*   rp   = (int*)(ws + N);
    int*   bsum = rp + (N + 4);
    int*   col  = bsum + 256;
    float* bufA = (float*)(col + E);
    float* bufB = bufA + (long)N * 128;

    float*          xfc  = bufA;
    unsigned short* h1bf = (unsigned short*)(bufA + (long)N * 64);
    unsigned short* f1bf = (unsigned short*)bufB;
    float*          aggx = bufB;
    float*          t2   = bufB;
    float*          z    = bufB + (long)N * 64;

    const int TB = 256;
    const int nb = (N + SCAN_B - 1) / SCAN_B;   // 196 <= 256

    // --- CSR build + normalization ---
    hipMemsetAsync(rp, 0, sizeof(int) * (size_t)(N + 1), stream);
    count_kernel<<<(E + TB - 1) / TB, TB, 0, stream>>>(dst, rp, E);
    dinv_kernel<<<(N + TB - 1) / TB, TB, 0, stream>>>(rp, dinv, N);
    scan1_kernel<<<nb, SCAN_B, 0, stream>>>(rp, bsum, N);
    scan2_kernel<<<1, SCAN_B, 0, stream>>>(bsum, nb);
    scan3_kernel<<<nb, SCAN_B, 0, stream>>>(rp, bsum, N);
    fill_kernel<<<(E + TB - 1) / TB, TB, 0, stream>>>(src, dst, rp, col, E);

    // --- FC path: f1 = relu(x@Wf1+bf1) [bf16], xfc = f1@Wf2 + bf2 ---
    {
        dim3 g(FFC / 64, (N + 63) / 64);
        gemm_t<0, 1><<<g, TB, 0, stream>>>(x, Wf1, bf1, f1bf, N, FFC, FIN, 1);
    }
    {
        dim3 g(FOUT / 64, (N + 63) / 64);
        gemm_t<1, 0><<<g, TB, 0, stream>>>(f1bf, Wf2, bf2, xfc, N, FOUT, FFC, 0);
    }

    // --- GCN layer 1: aggx = A_norm x ; h1 = relu(aggx@W1 + b1) [bf16] ---
    pull1_kernel<<<(N + 7) / 8, TB, 0, stream>>>(x, rp, col, dinv, aggx, N);
    {
        dim3 g(FHID / 64, (N + 63) / 64);
        gemm_t<0, 1><<<g, TB, 0, stream>>>(aggx, W1, b1, h1bf, N, FHID, FIN, 1);
    }

    // --- GCN layer 2: t2 = h1@W2 ; z = 0.5*(A_norm t2 + b2) + 0.5*xfc ---
    {
        dim3 g(FOUT / 64, (N + 63) / 64);
        gemm_t<1, 0><<<g, TB, 0, stream>>>(h1bf, W2, nullptr, t2, N, FOUT, FHID, 0);
    }
    pull2_kernel<<<(N + 15) / 16, TB, 0, stream>>>(t2, rp, col, dinv, xfc, b2, z, N);

    // --- decode ---
    {
        long total = (long)Q * 16;
        decode_kernel<<<(total + TB - 1) / TB, TB, 0, stream>>>(z, eli, out, Q);
    }
}

// Round 3
// 582.855 us; speedup vs baseline: 7.5560x; 1.2259x over previous
//
#include <hip/hip_runtime.h>

// Problem constants (shapes fixed by the reference).
#define FIN   128
#define FHID  128
#define FOUT  64
#define FFC   256
#define SCAN_B 256

typedef __attribute__((ext_vector_type(8))) short          bf16x8;
typedef __attribute__((ext_vector_type(4))) float          f32x4;
typedef __attribute__((ext_vector_type(8))) unsigned short u16x8;
typedef __attribute__((ext_vector_type(4))) unsigned short u16x4;

// ---------------------------------------------------------------------------
// bf16 helpers (raw ushort, RNE rounding)
static __device__ __forceinline__ unsigned short f2bf(float f) {
    unsigned int u = __float_as_uint(f);
    u = (u + 0x7fffu + ((u >> 16) & 1u)) >> 16;
    return (unsigned short)u;
}
static __device__ __forceinline__ float bf2f(unsigned short s) {
    return __uint_as_float(((unsigned int)s) << 16);
}

// ---------------------------------------------------------------------------
// dtype converts
__global__ void cvt_bf16_kernel(const float* __restrict__ in,
                                unsigned short* __restrict__ out, long n4) {
    long i = (long)blockIdx.x * blockDim.x + threadIdx.x;
    if (i >= n4) return;
    float4 v = ((const float4*)in)[i];
    ushort4 o = make_ushort4(f2bf(v.x), f2bf(v.y), f2bf(v.z), f2bf(v.w));
    ((ushort4*)out)[i] = o;
}

// W [K,Ncol] fp32 -> WT [Ncol,K] bf16
__global__ void cvt_wT_kernel(const float* __restrict__ W,
                              unsigned short* __restrict__ WT, int K, int Ncol) {
    int i = blockIdx.x * blockDim.x + threadIdx.x;
    if (i >= K * Ncol) return;
    int k = i / Ncol, n = i - k * Ncol;
    WT[(size_t)n * K + k] = f2bf(W[i]);
}

// ---------------------------------------------------------------------------
// CSR build
__global__ void count_kernel(const int* __restrict__ dst, int* __restrict__ rp, int E) {
    int i = blockIdx.x * blockDim.x + threadIdx.x;
    if (i < E) atomicAdd(&rp[dst[i]], 1);
}

__global__ void dinv_kernel(const int* __restrict__ cnt, float* __restrict__ dinv, int n) {
    int i = blockIdx.x * blockDim.x + threadIdx.x;
    if (i < n) dinv[i] = rsqrtf((float)cnt[i] + 1.0f);
}

__global__ void scan1_kernel(int* __restrict__ rp, int* __restrict__ bsum, int n) {
    __shared__ int tmp[SCAN_B];
    int tid = threadIdx.x;
    int i = blockIdx.x * SCAN_B + tid;
    int v = (i < n) ? rp[i] : 0;
    tmp[tid] = v;
    __syncthreads();
    int acc = v;
    for (int off = 1; off < SCAN_B; off <<= 1) {
        int a = (tid >= off) ? tmp[tid - off] : 0;
        __syncthreads();
        acc += a;
        tmp[tid] = acc;
        __syncthreads();
    }
    if (i < n) rp[i] = acc - v;
    if (tid == SCAN_B - 1) bsum[blockIdx.x] = acc;
}

__global__ void scan2_kernel(int* __restrict__ bsum, int nb) {
    __shared__ int tmp[SCAN_B];
    int tid = threadIdx.x;
    int v = (tid < nb) ? bsum[tid] : 0;
    tmp[tid] = v;
    __syncthreads();
    int acc = v;
    for (int off = 1; off < SCAN_B; off <<= 1) {
        int a = (tid >= off) ? tmp[tid - off] : 0;
        __syncthreads();
        acc += a;
        tmp[tid] = acc;
        __syncthreads();
    }
    if (tid < nb) bsum[tid] = acc - v;
}

__global__ void scan3_kernel(int* __restrict__ rp, const int* __restrict__ bsum, int n) {
    int i = blockIdx.x * SCAN_B + threadIdx.x;
    if (i < n) rp[i] += bsum[blockIdx.x];
}

__global__ void fill_kernel(const int* __restrict__ src, const int* __restrict__ dst,
                            int* __restrict__ rp, int* __restrict__ col, int E) {
    int e = blockIdx.x * blockDim.x + threadIdx.x;
    if (e < E) {
        int d = dst[e];
        int pos = atomicAdd(&rp[d], 1);
        col[pos] = src[e];
    }
}

// ---------------------------------------------------------------------------
// MFMA bf16 GEMM: C[M,Ncol] = A[M,K] @ B[K,Ncol], BT stored [Ncol,K] bf16.
// Block 256 = 4 waves; wave w -> rows [by*64 + w*16, +16), all 64 cols.
// Per k-step: 1 A-frag (16B/lane) + 4 B-frags, 4 MFMAs. fp32 accumulate.
template <int CBF, int RELU>
__global__ __launch_bounds__(256) void mfma_gemm(
    const unsigned short* __restrict__ A, const unsigned short* __restrict__ BT,
    const float* __restrict__ bias, void* __restrict__ Cv,
    int M, int Ncol, int K)
{
    const int lane = threadIdx.x & 63;
    const int wave = threadIdx.x >> 6;
    const int m = lane & 15;          // A row / D col within subtile
    const int q = lane >> 4;          // quad
    const int rowbase = blockIdx.y * 64 + wave * 16;
    const int row = rowbase + m;
    const int col0 = blockIdx.x * 64;

    f32x4 acc[4] = {};

    const unsigned short* arow = A + (size_t)row * K + q * 8;
    const unsigned short* brow0 = BT + (size_t)(col0 + m) * K + q * 8;

    for (int k0 = 0; k0 < K; k0 += 32) {
        bf16x8 a = {};
        if (row < M) a = *(const bf16x8*)(arow + k0);
        #pragma unroll
        for (int c = 0; c < 4; c++) {
            bf16x8 b = *(const bf16x8*)(brow0 + (size_t)c * 16 * K + k0);
            acc[c] = __builtin_amdgcn_mfma_f32_16x16x32_bf16(a, b, acc[c], 0, 0, 0);
        }
    }

    // D layout: col = lane&15, row = q*4 + reg
    #pragma unroll
    for (int c = 0; c < 4; c++) {
        int gc = col0 + c * 16 + m;
        float bv = bias ? bias[gc] : 0.0f;
        #pragma unroll
        for (int r = 0; r < 4; r++) {
            int gr = rowbase + q * 4 + r;
            if (gr >= M) continue;
            float v = acc[c][r] + bv;
            if (RELU) v = fmaxf(v, 0.f);
            if (CBF) ((unsigned short*)Cv)[(size_t)gr * Ncol + gc] = f2bf(v);
            else     ((float*)Cv)[(size_t)gr * Ncol + gc] = v;
        }
    }
}

// ---------------------------------------------------------------------------
// CSR pull, F=128 bf16 in/out: aggx[i] = di*(sum_{s} d_s*x[s] + di*x[i])
// 16 lanes/node, 8 bf16 (16B) per lane; fp32 accumulation.
__global__ __launch_bounds__(256) void pull1_kernel(
    const unsigned short* __restrict__ xbf, const int* __restrict__ rp,
    const int* __restrict__ col, const float* __restrict__ dinv,
    unsigned short* __restrict__ aggx, int N)
{
    int tid = threadIdx.x;
    int node = blockIdx.x * 16 + (tid >> 4);
    if (node >= N) return;
    int f0 = (tid & 15) << 3;
    float di = dinv[node];
    u16x8 xi = *(const u16x8*)(xbf + (size_t)node * FIN + f0);
    float acc[8];
    #pragma unroll
    for (int j = 0; j < 8; j++) acc[j] = di * bf2f(xi[j]);
    int beg = node ? rp[node - 1] : 0;
    int end = rp[node];
    for (int e = beg; e < end; e++) {
        int s = col[e];
        float w = dinv[s];
        u16x8 v = *(const u16x8*)(xbf + (size_t)s * FIN + f0);
        #pragma unroll
        for (int j = 0; j < 8; j++) acc[j] += w * bf2f(v[j]);
    }
    u16x8 o;
    #pragma unroll
    for (int j = 0; j < 8; j++) o[j] = f2bf(di * acc[j]);
    *(u16x8*)(aggx + (size_t)node * FIN + f0) = o;
}

// CSR pull, F=64 bf16 in, fused self-loop + bias + blend, fp32 out:
// z[i] = 0.5*(di*(sum + di*t2[i]) + b2) + 0.5*xfc[i]
__global__ __launch_bounds__(256) void pull2_kernel(
    const unsigned short* __restrict__ t2, const int* __restrict__ rp,
    const int* __restrict__ col, const float* __restrict__ dinv,
    const float* __restrict__ xfc, const float* __restrict__ b2,
    float* __restrict__ z, int N)
{
    int tid = threadIdx.x;
    int node = blockIdx.x * 16 + (tid >> 4);
    if (node >= N) return;
    int f0 = (tid & 15) << 2;
    float di = dinv[node];
    u16x4 ti = *(const u16x4*)(t2 + (size_t)node * FOUT + f0);
    float acc[4];
    #pragma unroll
    for (int j = 0; j < 4; j++) acc[j] = di * bf2f(ti[j]);
    int beg = node ? rp[node - 1] : 0;
    int end = rp[node];
    for (int e = beg; e < end; e++) {
        int s = col[e];
        float w = dinv[s];
        u16x4 v = *(const u16x4*)(t2 + (size_t)s * FOUT + f0);
        #pragma unroll
        for (int j = 0; j < 4; j++) acc[j] += w * bf2f(v[j]);
    }
    float4 bb = *(const float4*)(b2 + f0);
    float4 xf = *(const float4*)(xfc + (size_t)node * FOUT + f0);
    float4 o;
    o.x = 0.5f * (di * acc[0] + bb.x) + 0.5f * xf.x;
    o.y = 0.5f * (di * acc[1] + bb.y) + 0.5f * xf.y;
    o.z = 0.5f * (di * acc[2] + bb.z) + 0.5f * xf.z;
    o.w = 0.5f * (di * acc[3] + bb.w) + 0.5f * xf.w;
    *(float4*)(z + (size_t)node * FOUT + f0) = o;
}

// out[q] = dot(z[a], z[b]) over 64 dims; 16 threads/query, float4 each.
__global__ void decode_kernel(
    const float* __restrict__ z, const int* __restrict__ eli,
    float* __restrict__ out, int Q)
{
    int tid = blockIdx.x * blockDim.x + threadIdx.x;
    int q = tid >> 4;
    if (q >= Q) return;
    int lane = tid & 15;
    int a = eli[q];
    int b = eli[Q + q];
    float4 va = *(const float4*)(z + (size_t)a * FOUT + lane * 4);
    float4 vb = *(const float4*)(z + (size_t)b * FOUT + lane * 4);
    float s = va.x * vb.x + va.y * vb.y + va.z * vb.z + va.w * vb.w;
    s += __shfl_down(s, 8, 16);
    s += __shfl_down(s, 4, 16);
    s += __shfl_down(s, 2, 16);
    s += __shfl_down(s, 1, 16);
    if (lane == 0) out[q] = s;
}

// ---------------------------------------------------------------------------
extern "C" void kernel_launch(void* const* d_in, const int* in_sizes, int n_in,
                              void* d_out, int out_size, void* d_ws, size_t ws_size,
                              hipStream_t stream)
{
    const float* x   = (const float*)d_in[0];
    const int*   ei  = (const int*)  d_in[1];
    const int*   eli = (const int*)  d_in[2];
    const float* W1  = (const float*)d_in[3];
    const float* b1  = (const float*)d_in[4];
    const float* W2  = (const float*)d_in[5];
    const float* b2  = (const float*)d_in[6];
    const float* Wf1 = (const float*)d_in[7];
    const float* bf1 = (const float*)d_in[8];
    const float* Wf2 = (const float*)d_in[9];
    const float* bf2 = (const float*)d_in[10];
    float* out = (float*)d_out;

    const int N = in_sizes[0] / FIN;       // 50000
    const int E = in_sizes[1] / 2;         // 1600000
    const int Q = in_sizes[2] / 2;         // 500000
    const int* src = ei;
    const int* dst = ei + E;

    // Workspace layout (bytes; everything 16B-aligned). Peak ~58 MB.
    char* p = (char*)d_ws;
    float* dinv = (float*)p;             p += (size_t)N * 4;            // 200000
    int*   rp   = (int*)p;               p += (size_t)(N + 4) * 4;      // 200016
    int*   bsum = (int*)p;               p += 1024;
    int*   col  = (int*)p;               p += (size_t)E * 4;            // 6.4 MB
    unsigned short* xbf  = (unsigned short*)p; p += (size_t)N * FIN * 2;  // 12.8 MB
    unsigned short* w1t  = (unsigned short*)p; p += FIN * FHID * 2;
    unsigned short* w2t  = (unsigned short*)p; p += FHID * FOUT * 2;
    unsigned short* wf1t = (unsigned short*)p; p += FIN * FFC * 2;
    unsigned short* wf2t = (unsigned short*)p; p += FFC * FOUT * 2;
    float* xfc = (float*)p;              p += (size_t)N * FOUT * 4;     // 12.8 MB
    char*  S   = p;                                                     // 25.6 MB scratch
    unsigned short* f1   = (unsigned short*)S;                          // N*256 bf16
    unsigned short* aggx = (unsigned short*)S;                          // N*128 bf16
    unsigned short* h1   = (unsigned short*)(S + (size_t)N * FIN * 2);  // N*128 bf16
    unsigned short* t2   = (unsigned short*)S;                          // N*64 bf16
    float*          z    = (float*)(S + (size_t)N * FOUT * 2);          // N*64 f32

    const int TB = 256;
    const int nb = (N + SCAN_B - 1) / SCAN_B;

    // --- converts ---
    {
        long n4 = (long)N * FIN / 4;
        cvt_bf16_kernel<<<(n4 + TB - 1) / TB, TB, 0, stream>>>(x, xbf, n4);
    }
    cvt_wT_kernel<<<(FIN * FHID + TB - 1) / TB, TB, 0, stream>>>(W1, w1t, FIN, FHID);
    cvt_wT_kernel<<<(FHID * FOUT + TB - 1) / TB, TB, 0, stream>>>(W2, w2t, FHID, FOUT);
    cvt_wT_kernel<<<(FIN * FFC + TB - 1) / TB, TB, 0, stream>>>(Wf1, wf1t, FIN, FFC);
    cvt_wT_kernel<<<(FFC * FOUT + TB - 1) / TB, TB, 0, stream>>>(Wf2, wf2t, FFC, FOUT);

    // --- CSR build + normalization ---
    hipMemsetAsync(rp, 0, sizeof(int) * (size_t)(N + 1), stream);
    count_kernel<<<(E + TB - 1) / TB, TB, 0, stream>>>(dst, rp, E);
    dinv_kernel<<<(N + TB - 1) / TB, TB, 0, stream>>>(rp, dinv, N);
    scan1_kernel<<<nb, SCAN_B, 0, stream>>>(rp, bsum, N);
    scan2_kernel<<<1, SCAN_B, 0, stream>>>(bsum, nb);
    scan3_kernel<<<nb, SCAN_B, 0, stream>>>(rp, bsum, N);
    fill_kernel<<<(E + TB - 1) / TB, TB, 0, stream>>>(src, dst, rp, col, E);

    // --- FC path: f1 = relu(x@Wf1+bf1) [bf16]; xfc = f1@Wf2+bf2 [f32] ---
    {
        dim3 g(FFC / 64, (N + 63) / 64);
        mfma_gemm<1, 1><<<g, TB, 0, stream>>>(xbf, wf1t, bf1, f1, N, FFC, FIN);
    }
    {
        dim3 g(FOUT / 64, (N + 63) / 64);
        mfma_gemm<0, 0><<<g, TB, 0, stream>>>(f1, wf2t, bf2, xfc, N, FOUT, FFC);
    }

    // --- GCN layer 1: aggx = A_norm x [bf16]; h1 = relu(aggx@W1+b1) [bf16] ---
    pull1_kernel<<<(N + 15) / 16, TB, 0, stream>>>(xbf, rp, col, dinv, aggx, N);
    {
        dim3 g(FHID / 64, (N + 63) / 64);
        mfma_gemm<1, 1><<<g, TB, 0, stream>>>(aggx, w1t, b1, h1, N, FHID, FIN);
    }

    // --- GCN layer 2: t2 = h1@W2 [bf16]; z = 0.5*(A_norm t2 + b2) + 0.5*xfc ---
    {
        dim3 g(FOUT / 64, (N + 63) / 64);
        mfma_gemm<1, 0><<<g, TB, 0, stream>>>(h1, w2t, nullptr, t2, N, FOUT, FHID);
    }
    pull2_kernel<<<(N + 15) / 16, TB, 0, stream>>>(t2, rp, col, dinv, xfc, b2, z, N);

    // --- decode ---
    {
        long total = (long)Q * 16;
        decode_kernel<<<(total + TB - 1) / TB, TB, 0, stream>>>(z, eli, out, Q);
    }
}

// Round 4
// 460.246 us; speedup vs baseline: 9.5689x; 1.2664x over previous
//
#include <hip/hip_runtime.h>

// Problem constants (shapes fixed by the reference).
#define FIN   128
#define FHID  128
#define FOUT  64
#define FFC   256
#define CHUNK 4096     // edges per binA block

typedef __attribute__((ext_vector_type(8))) short          bf16x8;
typedef __attribute__((ext_vector_type(4))) float          f32x4;
typedef __attribute__((ext_vector_type(8))) unsigned short u16x8;
typedef __attribute__((ext_vector_type(4))) unsigned short u16x4;

// ---------------------------------------------------------------------------
// bf16 helpers (raw ushort, RNE rounding)
static __device__ __forceinline__ unsigned short f2bf(float f) {
    unsigned int u = __float_as_uint(f);
    u = (u + 0x7fffu + ((u >> 16) & 1u)) >> 16;
    return (unsigned short)u;
}
static __device__ __forceinline__ float bf2f(unsigned short s) {
    return __uint_as_float(((unsigned int)s) << 16);
}

// ---------------------------------------------------------------------------
// dtype converts
__global__ void cvt_bf16_kernel(const float* __restrict__ in,
                                unsigned short* __restrict__ out, long n4) {
    long i = (long)blockIdx.x * blockDim.x + threadIdx.x;
    if (i >= n4) return;
    float4 v = ((const float4*)in)[i];
    ushort4 o = make_ushort4(f2bf(v.x), f2bf(v.y), f2bf(v.z), f2bf(v.w));
    ((ushort4*)out)[i] = o;
}

// W [K,Ncol] fp32 -> WT [Ncol,K] bf16
__global__ void cvt_wT_kernel(const float* __restrict__ W,
                              unsigned short* __restrict__ WT, int K, int Ncol) {
    int i = blockIdx.x * blockDim.x + threadIdx.x;
    if (i >= K * Ncol) return;
    int k = i / Ncol, n = i - k * Ncol;
    WT[(size_t)n * K + k] = f2bf(W[i]);
}

// ---------------------------------------------------------------------------
// Bucketed CSR build. Bucket b = dst >> 8 (256 nodes per bucket).
// Phase 0: per-bucket edge histogram.
__global__ __launch_bounds__(256) void hist_kernel(
    const int* __restrict__ dst, int* __restrict__ bhist, int E, int NBK)
{
    __shared__ int h[256];
    int t = threadIdx.x;
    h[t] = 0;
    __syncthreads();
    for (int e = blockIdx.x * blockDim.x + t; e < E; e += gridDim.x * blockDim.x)
        atomicAdd(&h[dst[e] >> 8], 1);
    __syncthreads();
    if (t < NBK && h[t]) atomicAdd(&bhist[t], h[t]);
}

// Phase 0b: exclusive scan of bucket totals -> bbase; init cursors.
__global__ __launch_bounds__(256) void bscan_kernel(
    const int* __restrict__ bhist, int* __restrict__ bbase,
    int* __restrict__ bcur, int NBK)
{
    __shared__ int tmp[256];
    int t = threadIdx.x;
    int v = (t < NBK) ? bhist[t] : 0;
    tmp[t] = v;
    __syncthreads();
    int acc = v;
    for (int off = 1; off < 256; off <<= 1) {
        int a = (t >= off) ? tmp[t - off] : 0;
        __syncthreads();
        acc += a; tmp[t] = acc;
        __syncthreads();
    }
    if (t < NBK) { bbase[t] = acc - v; bcur[t] = acc - v; }
}

// Phase A: bin edges into bucket-partitioned ebuf (uint2 = (src,dst)).
// Per block: LDS histogram of its CHUNK, one global cursor reservation per
// bucket, then scatter -> writes are ~21-edge contiguous runs per bucket.
__global__ __launch_bounds__(256) void binA_kernel(
    const int* __restrict__ src, const int* __restrict__ dst,
    int* __restrict__ bcur, uint2* __restrict__ ebuf, int E, int NBK)
{
    __shared__ int hist[256];
    __shared__ int rstart[256];
    __shared__ int lcur[256];
    int t = threadIdx.x;
    hist[t] = 0; lcur[t] = 0;
    __syncthreads();
    int e0 = blockIdx.x * CHUNK;
    int e1 = min(e0 + CHUNK, E);
    for (int e = e0 + t; e < e1; e += 256)
        atomicAdd(&hist[dst[e] >> 8], 1);
    __syncthreads();
    if (t < NBK && hist[t] > 0) rstart[t] = atomicAdd(&bcur[t], hist[t]);
    __syncthreads();
    for (int e = e0 + t; e < e1; e += 256) {
        int s = src[e], d = dst[e];
        int b = d >> 8;
        int pos = atomicAdd(&lcur[b], 1);
        ebuf[rstart[b] + pos] = make_uint2((unsigned)s, (unsigned)d);
    }
}

// Phase B: one block per bucket. LDS node counts -> dinv + rp (inclusive end),
// then place edges into col (writes confined to a ~32KB L2-hot window).
__global__ __launch_bounds__(256) void binB_kernel(
    const uint2* __restrict__ ebuf, const int* __restrict__ bbase,
    const int* __restrict__ bhist, int* __restrict__ rp,
    int* __restrict__ col, float* __restrict__ dinv, int N)
{
    __shared__ int cnt[256];
    __shared__ int tmp[256];
    __shared__ int ccur[256];
    int b = blockIdx.x;
    int t = threadIdx.x;
    int base = bbase[b];
    int ne = bhist[b];
    cnt[t] = 0;
    __syncthreads();
    for (int e = t; e < ne; e += 256)
        atomicAdd(&cnt[ebuf[base + e].y & 255], 1);
    __syncthreads();
    int node = b * 256 + t;
    int c = cnt[t];
    if (node < N) dinv[node] = rsqrtf((float)c + 1.0f);
    tmp[t] = c;
    __syncthreads();
    int acc = c;
    for (int off = 1; off < 256; off <<= 1) {
        int a = (t >= off) ? tmp[t - off] : 0;
        __syncthreads();
        acc += a; tmp[t] = acc;
        __syncthreads();
    }
    if (node < N) rp[node] = base + acc;    // inclusive end of node's segment
    ccur[t] = base + acc - c;               // start cursor
    __syncthreads();
    for (int e = t; e < ne; e += 256) {
        uint2 ed = ebuf[base + e];
        int pos = atomicAdd(&ccur[ed.y & 255], 1);
        col[pos] = (int)ed.x;
    }
}

// ---------------------------------------------------------------------------
// MFMA bf16 GEMM: C[M,Ncol] = A[M,K] @ B[K,Ncol], BT stored [Ncol,K] bf16.
template <int CBF, int RELU>
__global__ __launch_bounds__(256) void mfma_gemm(
    const unsigned short* __restrict__ A, const unsigned short* __restrict__ BT,
    const float* __restrict__ bias, void* __restrict__ Cv,
    int M, int Ncol, int K)
{
    const int lane = threadIdx.x & 63;
    const int wave = threadIdx.x >> 6;
    const int m = lane & 15;
    const int q = lane >> 4;
    const int rowbase = blockIdx.y * 64 + wave * 16;
    const int row = rowbase + m;
    const int col0 = blockIdx.x * 64;

    f32x4 acc[4] = {};

    const unsigned short* arow = A + (size_t)row * K + q * 8;
    const unsigned short* brow0 = BT + (size_t)(col0 + m) * K + q * 8;

    for (int k0 = 0; k0 < K; k0 += 32) {
        bf16x8 a = {};
        if (row < M) a = *(const bf16x8*)(arow + k0);
        #pragma unroll
        for (int c = 0; c < 4; c++) {
            bf16x8 b = *(const bf16x8*)(brow0 + (size_t)c * 16 * K + k0);
            acc[c] = __builtin_amdgcn_mfma_f32_16x16x32_bf16(a, b, acc[c], 0, 0, 0);
        }
    }

    #pragma unroll
    for (int c = 0; c < 4; c++) {
        int gc = col0 + c * 16 + m;
        float bv = bias ? bias[gc] : 0.0f;
        #pragma unroll
        for (int r = 0; r < 4; r++) {
            int gr = rowbase + q * 4 + r;
            if (gr >= M) continue;
            float v = acc[c][r] + bv;
            if (RELU) v = fmaxf(v, 0.f);
            if (CBF) ((unsigned short*)Cv)[(size_t)gr * Ncol + gc] = f2bf(v);
            else     ((float*)Cv)[(size_t)gr * Ncol + gc] = v;
        }
    }
}

// ---------------------------------------------------------------------------
// CSR pull, F=128 bf16 in/out: aggx[i] = di*(sum_{s} d_s*x[s] + di*x[i])
__global__ __launch_bounds__(256) void pull1_kernel(
    const unsigned short* __restrict__ xbf, const int* __restrict__ rp,
    const int* __restrict__ col, const float* __restrict__ dinv,
    unsigned short* __restrict__ aggx, int N)
{
    int tid = threadIdx.x;
    int node = blockIdx.x * 16 + (tid >> 4);
    if (node >= N) return;
    int f0 = (tid & 15) << 3;
    float di = dinv[node];
    u16x8 xi = *(const u16x8*)(xbf + (size_t)node * FIN + f0);
    float acc[8];
    #pragma unroll
    for (int j = 0; j < 8; j++) acc[j] = di * bf2f(xi[j]);
    int beg = node ? rp[node - 1] : 0;
    int end = rp[node];
    for (int e = beg; e < end; e++) {
        int s = col[e];
        float w = dinv[s];
        u16x8 v = *(const u16x8*)(xbf + (size_t)s * FIN + f0);
        #pragma unroll
        for (int j = 0; j < 8; j++) acc[j] += w * bf2f(v[j]);
    }
    u16x8 o;
    #pragma unroll
    for (int j = 0; j < 8; j++) o[j] = f2bf(di * acc[j]);
    *(u16x8*)(aggx + (size_t)node * FIN + f0) = o;
}

// CSR pull, F=64 bf16 in, fused self-loop + bias + blend, fp32 out.
__global__ __launch_bounds__(256) void pull2_kernel(
    const unsigned short* __restrict__ t2, const int* __restrict__ rp,
    const int* __restrict__ col, const float* __restrict__ dinv,
    const float* __restrict__ xfc, const float* __restrict__ b2,
    float* __restrict__ z, int N)
{
    int tid = threadIdx.x;
    int node = blockIdx.x * 16 + (tid >> 4);
    if (node >= N) return;
    int f0 = (tid & 15) << 2;
    float di = dinv[node];
    u16x4 ti = *(const u16x4*)(t2 + (size_t)node * FOUT + f0);
    float acc[4];
    #pragma unroll
    for (int j = 0; j < 4; j++) acc[j] = di * bf2f(ti[j]);
    int beg = node ? rp[node - 1] : 0;
    int end = rp[node];
    for (int e = beg; e < end; e++) {
        int s = col[e];
        float w = dinv[s];
        u16x4 v = *(const u16x4*)(t2 + (size_t)s * FOUT + f0);
        #pragma unroll
        for (int j = 0; j < 4; j++) acc[j] += w * bf2f(v[j]);
    }
    float4 bb = *(const float4*)(b2 + f0);
    float4 xf = *(const float4*)(xfc + (size_t)node * FOUT + f0);
    float4 o;
    o.x = 0.5f * (di * acc[0] + bb.x) + 0.5f * xf.x;
    o.y = 0.5f * (di * acc[1] + bb.y) + 0.5f * xf.y;
    o.z = 0.5f * (di * acc[2] + bb.z) + 0.5f * xf.z;
    o.w = 0.5f * (di * acc[3] + bb.w) + 0.5f * xf.w;
    *(float4*)(z + (size_t)node * FOUT + f0) = o;
}

// out[q] = dot(z[a], z[b]) over 64 dims; 16 threads/query, float4 each.
__global__ void decode_kernel(
    const float* __restrict__ z, const int* __restrict__ eli,
    float* __restrict__ out, int Q)
{
    int tid = blockIdx.x * blockDim.x + threadIdx.x;
    int q = tid >> 4;
    if (q >= Q) return;
    int lane = tid & 15;
    int a = eli[q];
    int b = eli[Q + q];
    float4 va = *(const float4*)(z + (size_t)a * FOUT + lane * 4);
    float4 vb = *(const float4*)(z + (size_t)b * FOUT + lane * 4);
    float s = va.x * vb.x + va.y * vb.y + va.z * vb.z + va.w * vb.w;
    s += __shfl_down(s, 8, 16);
    s += __shfl_down(s, 4, 16);
    s += __shfl_down(s, 2, 16);
    s += __shfl_down(s, 1, 16);
    if (lane == 0) out[q] = s;
}

// ---------------------------------------------------------------------------
extern "C" void kernel_launch(void* const* d_in, const int* in_sizes, int n_in,
                              void* d_out, int out_size, void* d_ws, size_t ws_size,
                              hipStream_t stream)
{
    const float* x   = (const float*)d_in[0];
    const int*   ei  = (const int*)  d_in[1];
    const int*   eli = (const int*)  d_in[2];
    const float* W1  = (const float*)d_in[3];
    const float* b1  = (const float*)d_in[4];
    const float* W2  = (const float*)d_in[5];
    const float* b2  = (const float*)d_in[6];
    const float* Wf1 = (const float*)d_in[7];
    const float* bf1 = (const float*)d_in[8];
    const float* Wf2 = (const float*)d_in[9];
    const float* bf2 = (const float*)d_in[10];
    float* out = (float*)d_out;

    const int N = in_sizes[0] / FIN;       // 50000
    const int E = in_sizes[1] / 2;         // 1600000
    const int Q = in_sizes[2] / 2;         // 500000
    const int* src = ei;
    const int* dst = ei + E;
    const int NBK = (N + 255) >> 8;        // 196 buckets

    // Workspace layout (bytes; 16B-aligned). Peak ~58 MB (ebuf aliases S).
    char* p = (char*)d_ws;
    float* dinv  = (float*)p;            p += (size_t)N * 4;
    int*   rp    = (int*)p;              p += (size_t)(N + 4) * 4;
    int*   bhist = (int*)p;              p += 1024;
    int*   bbase = (int*)p;              p += 1024;
    int*   bcur  = (int*)p;              p += 1024;
    int*   col   = (int*)p;              p += (size_t)E * 4;
    unsigned short* xbf  = (unsigned short*)p; p += (size_t)N * FIN * 2;
    unsigned short* w1t  = (unsigned short*)p; p += FIN * FHID * 2;
    unsigned short* w2t  = (unsigned short*)p; p += FHID * FOUT * 2;
    unsigned short* wf1t = (unsigned short*)p; p += FIN * FFC * 2;
    unsigned short* wf2t = (unsigned short*)p; p += FFC * FOUT * 2;
    float* xfc = (float*)p;              p += (size_t)N * FOUT * 4;
    char*  S   = p;                      // 25.6 MB scratch
    uint2*          ebuf = (uint2*)S;                                   // E*8 B (dead before f1)
    unsigned short* f1   = (unsigned short*)S;                          // N*256 bf16
    unsigned short* aggx = (unsigned short*)S;                          // N*128 bf16
    unsigned short* h1   = (unsigned short*)(S + (size_t)N * FIN * 2);  // N*128 bf16
    unsigned short* t2   = (unsigned short*)S;                          // N*64 bf16
    float*          z    = (float*)(S + (size_t)N * FOUT * 2);          // N*64 f32

    const int TB = 256;

    // --- converts ---
    {
        long n4 = (long)N * FIN / 4;
        cvt_bf16_kernel<<<(n4 + TB - 1) / TB, TB, 0, stream>>>(x, xbf, n4);
    }
    cvt_wT_kernel<<<(FIN * FHID + TB - 1) / TB, TB, 0, stream>>>(W1, w1t, FIN, FHID);
    cvt_wT_kernel<<<(FHID * FOUT + TB - 1) / TB, TB, 0, stream>>>(W2, w2t, FHID, FOUT);
    cvt_wT_kernel<<<(FIN * FFC + TB - 1) / TB, TB, 0, stream>>>(Wf1, wf1t, FIN, FFC);
    cvt_wT_kernel<<<(FFC * FOUT + TB - 1) / TB, TB, 0, stream>>>(Wf2, wf2t, FFC, FOUT);

    // --- bucketed CSR build ---
    hipMemsetAsync(bhist, 0, 1024, stream);
    hist_kernel<<<1024, TB, 0, stream>>>(dst, bhist, E, NBK);
    bscan_kernel<<<1, TB, 0, stream>>>(bhist, bbase, bcur, NBK);
    binA_kernel<<<(E + CHUNK - 1) / CHUNK, TB, 0, stream>>>(src, dst, bcur, ebuf, E, NBK);
    binB_kernel<<<NBK, TB, 0, stream>>>(ebuf, bbase, bhist, rp, col, dinv, N);

    // --- FC path: f1 = relu(x@Wf1+bf1) [bf16]; xfc = f1@Wf2+bf2 [f32] ---
    {
        dim3 g(FFC / 64, (N + 63) / 64);
        mfma_gemm<1, 1><<<g, TB, 0, stream>>>(xbf, wf1t, bf1, f1, N, FFC, FIN);
    }
    {
        dim3 g(FOUT / 64, (N + 63) / 64);
        mfma_gemm<0, 0><<<g, TB, 0, stream>>>(f1, wf2t, bf2, xfc, N, FOUT, FFC);
    }

    // --- GCN layer 1: aggx = A_norm x [bf16]; h1 = relu(aggx@W1+b1) [bf16] ---
    pull1_kernel<<<(N + 15) / 16, TB, 0, stream>>>(xbf, rp, col, dinv, aggx, N);
    {
        dim3 g(FHID / 64, (N + 63) / 64);
        mfma_gemm<1, 1><<<g, TB, 0, stream>>>(aggx, w1t, b1, h1, N, FHID, FIN);
    }

    // --- GCN layer 2: t2 = h1@W2 [bf16]; z = 0.5*(A_norm t2 + b2) + 0.5*xfc ---
    {
        dim3 g(FOUT / 64, (N + 63) / 64);
        mfma_gemm<1, 0><<<g, TB, 0, stream>>>(h1, w2t, nullptr, t2, N, FOUT, FHID);
    }
    pull2_kernel<<<(N + 15) / 16, TB, 0, stream>>>(t2, rp, col, dinv, xfc, b2, z, N);

    // --- decode ---
    {
        long total = (long)Q * 16;
        decode_kernel<<<(total + TB - 1) / TB, TB, 0, stream>>>(z, eli, out, Q);
    }
}

// Round 5
// 430.361 us; speedup vs baseline: 10.2334x; 1.0694x over previous
//
#include <hip/hip_runtime.h>

// Problem constants (shapes fixed by the reference).
#define FIN   128
#define FHID  128
#define FOUT  64
#define FFC   256
#define CHUNK 4096     // edges per binA block

typedef __attribute__((ext_vector_type(8))) short          bf16x8;
typedef __attribute__((ext_vector_type(4))) float          f32x4;
typedef __attribute__((ext_vector_type(8))) unsigned short u16x8;

// ---------------------------------------------------------------------------
// bf16 helpers (raw ushort, RNE rounding)
static __device__ __forceinline__ unsigned short f2bf(float f) {
    unsigned int u = __float_as_uint(f);
    u = (u + 0x7fffu + ((u >> 16) & 1u)) >> 16;
    return (unsigned short)u;
}
static __device__ __forceinline__ float bf2f(unsigned short s) {
    return __uint_as_float(((unsigned int)s) << 16);
}

// ---------------------------------------------------------------------------
// x fp32 -> bf16
__global__ void cvt_bf16_kernel(const float* __restrict__ in,
                                unsigned short* __restrict__ out, long n4) {
    long i = (long)blockIdx.x * blockDim.x + threadIdx.x;
    if (i >= n4) return;
    float4 v = ((const float4*)in)[i];
    ushort4 o = make_ushort4(f2bf(v.x), f2bf(v.y), f2bf(v.z), f2bf(v.w));
    ((ushort4*)out)[i] = o;
}

// all four weights fp32 [K,N] -> bf16 [N,K], one kernel
__global__ void cvt_weights_kernel(
    const float* __restrict__ W1, const float* __restrict__ W2,
    const float* __restrict__ Wf1, const float* __restrict__ Wf2,
    unsigned short* __restrict__ w1t, unsigned short* __restrict__ w2t,
    unsigned short* __restrict__ wf1t, unsigned short* __restrict__ wf2t)
{
    int i = blockIdx.x * blockDim.x + threadIdx.x;
    if (i < 16384) {                       // W1 [128,128]
        int k = i >> 7, n = i & 127;
        w1t[n * 128 + k] = f2bf(W1[i]);
    } else if (i < 24576) {                // W2 [128,64]
        int j = i - 16384; int k = j >> 6, n = j & 63;
        w2t[n * 128 + k] = f2bf(W2[j]);
    } else if (i < 57344) {                // Wf1 [128,256]
        int j = i - 24576; int k = j >> 8, n = j & 255;
        wf1t[n * 128 + k] = f2bf(Wf1[j]);
    } else if (i < 73728) {                // Wf2 [256,64]
        int j = i - 57344; int k = j >> 6, n = j & 63;
        wf2t[n * 256 + k] = f2bf(Wf2[j]);
    }
}

// xs = dinv[node] * x  (bf16, row-scaled feature table for pull1)
__global__ void scale_x_kernel(const unsigned short* __restrict__ xbf,
                               const float* __restrict__ dinv,
                               unsigned short* __restrict__ xs, long n8) {
    long i = (long)blockIdx.x * blockDim.x + threadIdx.x;
    if (i >= n8) return;
    int node = (int)(i >> 4);              // 16 groups of 8 per 128-feat row
    float di = dinv[node];
    u16x8 v = ((const u16x8*)xbf)[i];
    u16x8 o;
    #pragma unroll
    for (int j = 0; j < 8; j++) o[j] = f2bf(di * bf2f(v[j]));
    ((u16x8*)xs)[i] = o;
}

// ---------------------------------------------------------------------------
// Bucketed CSR build. Bucket b = dst >> 8 (256 nodes per bucket).
__global__ __launch_bounds__(256) void hist_kernel(
    const int* __restrict__ dst, int* __restrict__ bhist, int E, int NBK)
{
    __shared__ int h[256];
    int t = threadIdx.x;
    h[t] = 0;
    __syncthreads();
    for (int e = blockIdx.x * blockDim.x + t; e < E; e += gridDim.x * blockDim.x)
        atomicAdd(&h[dst[e] >> 8], 1);
    __syncthreads();
    if (t < NBK && h[t]) atomicAdd(&bhist[t], h[t]);
}

__global__ __launch_bounds__(256) void bscan_kernel(
    const int* __restrict__ bhist, int* __restrict__ bbase,
    int* __restrict__ bcur, int NBK)
{
    __shared__ int tmp[256];
    int t = threadIdx.x;
    int v = (t < NBK) ? bhist[t] : 0;
    tmp[t] = v;
    __syncthreads();
    int acc = v;
    for (int off = 1; off < 256; off <<= 1) {
        int a = (t >= off) ? tmp[t - off] : 0;
        __syncthreads();
        acc += a; tmp[t] = acc;
        __syncthreads();
    }
    if (t < NBK) { bbase[t] = acc - v; bcur[t] = acc - v; }
}

__global__ __launch_bounds__(256) void binA_kernel(
    const int* __restrict__ src, const int* __restrict__ dst,
    int* __restrict__ bcur, uint2* __restrict__ ebuf, int E, int NBK)
{
    __shared__ int hist[256];
    __shared__ int rstart[256];
    __shared__ int lcur[256];
    int t = threadIdx.x;
    hist[t] = 0; lcur[t] = 0;
    __syncthreads();
    int e0 = blockIdx.x * CHUNK;
    int e1 = min(e0 + CHUNK, E);
    for (int e = e0 + t; e < e1; e += 256)
        atomicAdd(&hist[dst[e] >> 8], 1);
    __syncthreads();
    if (t < NBK && hist[t] > 0) rstart[t] = atomicAdd(&bcur[t], hist[t]);
    __syncthreads();
    for (int e = e0 + t; e < e1; e += 256) {
        int s = src[e], d = dst[e];
        int b = d >> 8;
        int pos = atomicAdd(&lcur[b], 1);
        ebuf[rstart[b] + pos] = make_uint2((unsigned)s, (unsigned)d);
    }
}

__global__ __launch_bounds__(256) void binB_kernel(
    const uint2* __restrict__ ebuf, const int* __restrict__ bbase,
    const int* __restrict__ bhist, int* __restrict__ rp,
    int* __restrict__ col, float* __restrict__ dinv, int N)
{
    __shared__ int cnt[256];
    __shared__ int tmp[256];
    __shared__ int ccur[256];
    int b = blockIdx.x;
    int t = threadIdx.x;
    int base = bbase[b];
    int ne = bhist[b];
    cnt[t] = 0;
    __syncthreads();
    for (int e = t; e < ne; e += 256)
        atomicAdd(&cnt[ebuf[base + e].y & 255], 1);
    __syncthreads();
    int node = b * 256 + t;
    int c = cnt[t];
    if (node < N) dinv[node] = rsqrtf((float)c + 1.0f);
    tmp[t] = c;
    __syncthreads();
    int acc = c;
    for (int off = 1; off < 256; off <<= 1) {
        int a = (t >= off) ? tmp[t - off] : 0;
        __syncthreads();
        acc += a; tmp[t] = acc;
        __syncthreads();
    }
    if (node < N) rp[node] = base + acc;    // inclusive end of node's segment
    ccur[t] = base + acc - c;               // start cursor
    __syncthreads();
    for (int e = t; e < ne; e += 256) {
        uint2 ed = ebuf[base + e];
        int pos = atomicAdd(&ccur[ed.y & 255], 1);
        col[pos] = (int)ed.x;
    }
}

// ---------------------------------------------------------------------------
// MFMA bf16 GEMM: C[M,Ncol] = A[M,K] @ B[K,Ncol], BT stored [Ncol,K] bf16.
// CF = column fragments per wave (Ncol = CF*16 when grid.x==1 -> A read once).
template <int CF, int CBF, int RELU, int SCALE>
__global__ __launch_bounds__(256) void mfma_gemm(
    const unsigned short* __restrict__ A, const unsigned short* __restrict__ BT,
    const float* __restrict__ bias, const float* __restrict__ rowscale,
    void* __restrict__ Cv, int M, int Ncol, int K)
{
    const int lane = threadIdx.x & 63;
    const int wave = threadIdx.x >> 6;
    const int m = lane & 15;
    const int q = lane >> 4;
    const int rowbase = blockIdx.y * 64 + wave * 16;
    const int row = rowbase + m;
    const int col0 = blockIdx.x * (CF * 16);

    f32x4 acc[CF] = {};

    const unsigned short* arow = A + (size_t)row * K + q * 8;
    const unsigned short* brow = BT + (size_t)(col0 + m) * K + q * 8;

    for (int k0 = 0; k0 < K; k0 += 32) {
        bf16x8 a = {};
        if (row < M) a = *(const bf16x8*)(arow + k0);
        #pragma unroll
        for (int c = 0; c < CF; c++) {
            bf16x8 b = *(const bf16x8*)(brow + (size_t)c * 16 * K + k0);
            acc[c] = __builtin_amdgcn_mfma_f32_16x16x32_bf16(a, b, acc[c], 0, 0, 0);
        }
    }

    float rs[4];
    #pragma unroll
    for (int r = 0; r < 4; r++) {
        int gr = rowbase + q * 4 + r;
        rs[r] = (SCALE && gr < M) ? rowscale[gr] : 1.0f;
    }

    #pragma unroll
    for (int c = 0; c < CF; c++) {
        int gc = col0 + c * 16 + m;
        float bv = bias ? bias[gc] : 0.0f;
        #pragma unroll
        for (int r = 0; r < 4; r++) {
            int gr = rowbase + q * 4 + r;
            if (gr >= M) continue;
            float v = acc[c][r] + bv;
            if (SCALE) v *= rs[r];
            if (RELU) v = fmaxf(v, 0.f);
            if (CBF) ((unsigned short*)Cv)[(size_t)gr * Ncol + gc] = f2bf(v);
            else     ((float*)Cv)[(size_t)gr * Ncol + gc] = v;
        }
    }
}

// ---------------------------------------------------------------------------
// CSR pull, F=128, pre-scaled rows: aggx[i] = di*(xs[i] + sum_s xs[s])
// 16 lanes/node, 16B/lane, 4x edge unroll.
__global__ __launch_bounds__(256) void pull1_kernel(
    const unsigned short* __restrict__ xs, const int* __restrict__ rp,
    const int* __restrict__ col, const float* __restrict__ dinv,
    unsigned short* __restrict__ aggx, int N)
{
    int tid = threadIdx.x;
    int node = blockIdx.x * 16 + (tid >> 4);
    if (node >= N) return;
    int f0 = (tid & 15) << 3;
    const unsigned short* base = xs + f0;
    u16x8 own = *(const u16x8*)(base + (size_t)node * FIN);
    float acc[8];
    #pragma unroll
    for (int j = 0; j < 8; j++) acc[j] = bf2f(own[j]);
    int e = node ? rp[node - 1] : 0;
    int end = rp[node];
    for (; e + 4 <= end; e += 4) {
        int s0 = col[e], s1 = col[e + 1], s2 = col[e + 2], s3 = col[e + 3];
        u16x8 v0 = *(const u16x8*)(base + (size_t)s0 * FIN);
        u16x8 v1 = *(const u16x8*)(base + (size_t)s1 * FIN);
        u16x8 v2 = *(const u16x8*)(base + (size_t)s2 * FIN);
        u16x8 v3 = *(const u16x8*)(base + (size_t)s3 * FIN);
        #pragma unroll
        for (int j = 0; j < 8; j++)
            acc[j] += (bf2f(v0[j]) + bf2f(v1[j])) + (bf2f(v2[j]) + bf2f(v3[j]));
    }
    for (; e < end; e++) {
        u16x8 v = *(const u16x8*)(base + (size_t)col[e] * FIN);
        #pragma unroll
        for (int j = 0; j < 8; j++) acc[j] += bf2f(v[j]);
    }
    float di = dinv[node];
    u16x8 o;
    #pragma unroll
    for (int j = 0; j < 8; j++) o[j] = f2bf(di * acc[j]);
    *(u16x8*)(aggx + (size_t)node * FIN + f0) = o;
}

// CSR pull, F=64, pre-scaled rows, fused bias+blend; bf16 z out.
// 8 lanes/node, 16B/lane, 4x edge unroll.
__global__ __launch_bounds__(256) void pull2_kernel(
    const unsigned short* __restrict__ t2s, const int* __restrict__ rp,
    const int* __restrict__ col, const float* __restrict__ dinv,
    const float* __restrict__ xfc, const float* __restrict__ b2,
    unsigned short* __restrict__ zbf, int N)
{
    int tid = threadIdx.x;
    int node = blockIdx.x * 32 + (tid >> 3);
    if (node >= N) return;
    int f0 = (tid & 7) << 3;
    const unsigned short* base = t2s + f0;
    u16x8 own = *(const u16x8*)(base + (size_t)node * FOUT);
    float acc[8];
    #pragma unroll
    for (int j = 0; j < 8; j++) acc[j] = bf2f(own[j]);
    int e = node ? rp[node - 1] : 0;
    int end = rp[node];
    for (; e + 4 <= end; e += 4) {
        int s0 = col[e], s1 = col[e + 1], s2 = col[e + 2], s3 = col[e + 3];
        u16x8 v0 = *(const u16x8*)(base + (size_t)s0 * FOUT);
        u16x8 v1 = *(const u16x8*)(base + (size_t)s1 * FOUT);
        u16x8 v2 = *(const u16x8*)(base + (size_t)s2 * FOUT);
        u16x8 v3 = *(const u16x8*)(base + (size_t)s3 * FOUT);
        #pragma unroll
        for (int j = 0; j < 8; j++)
            acc[j] += (bf2f(v0[j]) + bf2f(v1[j])) + (bf2f(v2[j]) + bf2f(v3[j]));
    }
    for (; e < end; e++) {
        u16x8 v = *(const u16x8*)(base + (size_t)col[e] * FOUT);
        #pragma unroll
        for (int j = 0; j < 8; j++) acc[j] += bf2f(v[j]);
    }
    float di = dinv[node];
    float4 x0 = *(const float4*)(xfc + (size_t)node * FOUT + f0);
    float4 x1 = *(const float4*)(xfc + (size_t)node * FOUT + f0 + 4);
    float4 bb0 = *(const float4*)(b2 + f0);
    float4 bb1 = *(const float4*)(b2 + f0 + 4);
    float xf[8] = { x0.x, x0.y, x0.z, x0.w, x1.x, x1.y, x1.z, x1.w };
    float bv[8] = { bb0.x, bb0.y, bb0.z, bb0.w, bb1.x, bb1.y, bb1.z, bb1.w };
    u16x8 o;
    #pragma unroll
    for (int j = 0; j < 8; j++)
        o[j] = f2bf(0.5f * (di * acc[j] + bv[j]) + 0.5f * xf[j]);
    *(u16x8*)(zbf + (size_t)node * FOUT + f0) = o;
}

// out[q] = dot(z[a], z[b]) over 64 dims; 8 threads/query, 16B bf16 each.
__global__ void decode_kernel(
    const unsigned short* __restrict__ zbf, const int* __restrict__ eli,
    float* __restrict__ out, int Q)
{
    int tid = blockIdx.x * blockDim.x + threadIdx.x;
    int q = tid >> 3;
    if (q >= Q) return;
    int lane = tid & 7;
    int a = eli[q];
    int b = eli[Q + q];
    u16x8 va = *(const u16x8*)(zbf + (size_t)a * FOUT + lane * 8);
    u16x8 vb = *(const u16x8*)(zbf + (size_t)b * FOUT + lane * 8);
    float s = 0.f;
    #pragma unroll
    for (int j = 0; j < 8; j++) s += bf2f(va[j]) * bf2f(vb[j]);
    s += __shfl_down(s, 4, 8);
    s += __shfl_down(s, 2, 8);
    s += __shfl_down(s, 1, 8);
    if (lane == 0) out[q] = s;
}

// ---------------------------------------------------------------------------
extern "C" void kernel_launch(void* const* d_in, const int* in_sizes, int n_in,
                              void* d_out, int out_size, void* d_ws, size_t ws_size,
                              hipStream_t stream)
{
    const float* x   = (const float*)d_in[0];
    const int*   ei  = (const int*)  d_in[1];
    const int*   eli = (const int*)  d_in[2];
    const float* W1  = (const float*)d_in[3];
    const float* b1  = (const float*)d_in[4];
    const float* W2  = (const float*)d_in[5];
    const float* b2  = (const float*)d_in[6];
    const float* Wf1 = (const float*)d_in[7];
    const float* bf1 = (const float*)d_in[8];
    const float* Wf2 = (const float*)d_in[9];
    const float* bf2 = (const float*)d_in[10];
    float* out = (float*)d_out;

    const int N = in_sizes[0] / FIN;       // 50000
    const int E = in_sizes[1] / 2;         // 1600000
    const int Q = in_sizes[2] / 2;         // 500000
    const int* src = ei;
    const int* dst = ei + E;
    const int NBK = (N + 255) >> 8;        // 196 buckets

    // Workspace layout (bytes; 16B-aligned). Peak ~58 MB.
    char* p = (char*)d_ws;
    float* dinv  = (float*)p;            p += (size_t)N * 4;
    int*   rp    = (int*)p;              p += (size_t)(N + 4) * 4;
    int*   bhist = (int*)p;              p += 1024;
    int*   bbase = (int*)p;              p += 1024;
    int*   bcur  = (int*)p;              p += 1024;
    int*   col   = (int*)p;              p += (size_t)E * 4;
    unsigned short* xbf  = (unsigned short*)p; p += (size_t)N * FIN * 2;
    unsigned short* w1t  = (unsigned short*)p; p += FIN * FHID * 2;
    unsigned short* w2t  = (unsigned short*)p; p += FHID * FOUT * 2;
    unsigned short* wf1t = (unsigned short*)p; p += FIN * FFC * 2;
    unsigned short* wf2t = (unsigned short*)p; p += FFC * FOUT * 2;
    float* xfc = (float*)p;              p += (size_t)N * FOUT * 4;
    char*  S   = p;                      // 25.6 MB scratch, time-multiplexed:
    uint2*          ebuf = (uint2*)S;                                   // CSR build
    unsigned short* f1   = (unsigned short*)S;                          // N*256 bf16
    unsigned short* xs   = (unsigned short*)S;                          // N*128 bf16
    unsigned short* aggx = (unsigned short*)(S + (size_t)N * FIN * 2);  // N*128 bf16
    unsigned short* h1   = (unsigned short*)S;                          // N*128 bf16
    unsigned short* t2s  = (unsigned short*)(S + (size_t)N * FIN * 2);  // N*64 bf16
    unsigned short* zbf  = (unsigned short*)(S + (size_t)N * FIN * 2
                                               + (size_t)N * FOUT * 2); // N*64 bf16

    const int TB = 256;

    // --- converts ---
    {
        long n4 = (long)N * FIN / 4;
        cvt_bf16_kernel<<<(n4 + TB - 1) / TB, TB, 0, stream>>>(x, xbf, n4);
    }
    cvt_weights_kernel<<<(73728 + TB - 1) / TB, TB, 0, stream>>>(
        W1, W2, Wf1, Wf2, w1t, w2t, wf1t, wf2t);

    // --- bucketed CSR build (ebuf lives in S; dead before f1 is written) ---
    hipMemsetAsync(bhist, 0, 1024, stream);
    hist_kernel<<<1024, TB, 0, stream>>>(dst, bhist, E, NBK);
    bscan_kernel<<<1, TB, 0, stream>>>(bhist, bbase, bcur, NBK);
    binA_kernel<<<(E + CHUNK - 1) / CHUNK, TB, 0, stream>>>(src, dst, bcur, ebuf, E, NBK);
    binB_kernel<<<NBK, TB, 0, stream>>>(ebuf, bbase, bhist, rp, col, dinv, N);

    // --- FC path: f1 = relu(x@Wf1+bf1) [bf16]; xfc = f1@Wf2+bf2 [f32] ---
    {
        dim3 g(1, (N + 63) / 64);
        mfma_gemm<16, 1, 1, 0><<<g, TB, 0, stream>>>(xbf, wf1t, bf1, nullptr, f1, N, FFC, FIN);
    }
    {
        dim3 g(1, (N + 63) / 64);
        mfma_gemm<4, 0, 0, 0><<<g, TB, 0, stream>>>(f1, wf2t, bf2, nullptr, xfc, N, FOUT, FFC);
    }

    // --- GCN layer 1: xs = dinv*x; aggx = dinv*(xs[i] + sum xs); h1 = relu(aggx@W1+b1) ---
    {
        long n8 = (long)N * FIN / 8;
        scale_x_kernel<<<(n8 + TB - 1) / TB, TB, 0, stream>>>(xbf, dinv, xs, n8);
    }
    pull1_kernel<<<(N + 15) / 16, TB, 0, stream>>>(xs, rp, col, dinv, aggx, N);
    {
        dim3 g(1, (N + 63) / 64);
        mfma_gemm<8, 1, 1, 0><<<g, TB, 0, stream>>>(aggx, w1t, b1, nullptr, h1, N, FHID, FIN);
    }

    // --- GCN layer 2: t2s = dinv*(h1@W2) [bf16]; z = 0.5*(dinv*agg + b2) + 0.5*xfc [bf16] ---
    {
        dim3 g(1, (N + 63) / 64);
        mfma_gemm<4, 1, 0, 1><<<g, TB, 0, stream>>>(h1, w2t, nullptr, dinv, t2s, N, FOUT, FHID);
    }
    pull2_kernel<<<(N + 31) / 32, TB, 0, stream>>>(t2s, rp, col, dinv, xfc, b2, zbf, N);

    // --- decode ---
    {
        long total = (long)Q * 8;
        decode_kernel<<<(total + TB - 1) / TB, TB, 0, stream>>>(zbf, eli, out, Q);
    }
}